// Round 1
// baseline (166.099 us; speedup 1.0000x reference)
//
#include <hip/hip_runtime.h>

// Post_Prob_GS: B=8, N=256 points, grid 128x128 (HW=16384), stride 4.
// out[b, n, hw] = softmax over n in [0,257) of likelihood.
// likelihood[n<256] = z_n - 0.5*log(det_n); likelihood[256] = bk_like.

#define HWC 16384
#define NPTS 256
#define NBATCH 8

__global__ __launch_bounds__(256) void post_prob_kernel(
    const float* __restrict__ scale,     // (B, N, 2)
    const float* __restrict__ rotation,  // (B, N, 1)
    const float* __restrict__ points,    // (B, N, 2)
    float* __restrict__ out)             // (B, N+1, HW)
{
    __shared__ float sA[NPTS];   // -0.5 * inv_a
    __shared__ float sB[NPTS];   // -inv_b
    __shared__ float sD[NPTS];   // -0.5 * inv_d
    __shared__ float sHL[NPTS];  // -0.5 * log(det)
    __shared__ float sLD[NPTS];  // log(det)
    __shared__ float sPX[NPTS];
    __shared__ float sPY[NPTS];

    const int b  = blockIdx.x >> 6;                       // 64 blocks per batch
    const int hw = ((blockIdx.x & 63) << 8) + threadIdx.x;

    // ---- stage per-point params into LDS (one point per thread) ----
    {
        const int n = threadIdx.x;
        const int base = (b * NPTS + n);
        float sx = scale[base * 2 + 0];
        float sy = scale[base * 2 + 1];
        sx = fminf(fmaxf(32.0f * sx, 2.0f), 100.0f);
        sy = fminf(fmaxf(32.0f * sy, 2.0f), 100.0f);
        float sx2 = sx * sx, sy2 = sy * sy;
        float th = rotation[base];
        float c, si;
        __sincosf(th, &si, &c);
        float cov_a = c * c * sx2 + si * si * sy2;
        float cov_b = c * si * (sx2 - sy2);
        float cov_d = si * si * sx2 + c * c * sy2;
        float det   = sx2 * sy2;
        float rdet  = 1.0f / det;
        float inv_a = cov_d * rdet;
        float inv_b = -cov_b * rdet;
        float inv_d = cov_a * rdet;
        float logdet = logf(det);
        sA[n]  = -0.5f * inv_a;
        sB[n]  = -inv_b;
        sD[n]  = -0.5f * inv_d;
        sHL[n] = -0.5f * logdet;
        sLD[n] = logdet;
        sPX[n] = points[base * 2 + 0];
        sPY[n] = points[base * 2 + 1];
    }
    __syncthreads();

    const float gx = (float)((hw & 127) * 4 + 2);
    const float gy = (float)((hw >> 7) * 4 + 2);

    // ---- pass 1: running max of likelihood; first-argmax of z ----
    float m      = -INFINITY;
    float best_z = -INFINITY;
    int   best_n = 0;
    #pragma unroll 4
    for (int n = 0; n < NPTS; ++n) {
        float dx = gx - sPX[n];
        float dy = gy - sPY[n];
        float z  = sA[n] * dx * dx + sB[n] * (dx * dy) + sD[n] * dy * dy;
        float like = z + sHL[n];
        m = fmaxf(m, like);
        if (z > best_z) { best_z = z; best_n = n; }   // first occurrence wins
    }
    const float LOG_BG = -1.8971199848858813f;        // log(0.15)
    const float bk = -5000.0f - best_z - sLD[best_n] + LOG_BG;
    m = fmaxf(m, bk);

    // ---- pass 2: sum of exps ----
    float sum = 0.0f;
    #pragma unroll 4
    for (int n = 0; n < NPTS; ++n) {
        float dx = gx - sPX[n];
        float dy = gy - sPY[n];
        float z  = sA[n] * dx * dx + sB[n] * (dx * dy) + sD[n] * dy * dy;
        sum += __expf(z + sHL[n] - m);
    }
    sum += __expf(bk - m);
    const float inv = 1.0f / sum;

    // ---- pass 3: normalized writes (coalesced: lanes contiguous in hw) ----
    float* __restrict__ outb = out + (size_t)b * 257 * HWC + hw;
    #pragma unroll 4
    for (int n = 0; n < NPTS; ++n) {
        float dx = gx - sPX[n];
        float dy = gy - sPY[n];
        float z  = sA[n] * dx * dx + sB[n] * (dx * dy) + sD[n] * dy * dy;
        outb[(size_t)n * HWC] = __expf(z + sHL[n] - m) * inv;
    }
    outb[(size_t)256 * HWC] = __expf(bk - m) * inv;
}

extern "C" void kernel_launch(void* const* d_in, const int* in_sizes, int n_in,
                              void* d_out, int out_size, void* d_ws, size_t ws_size,
                              hipStream_t stream) {
    const float* scale    = (const float*)d_in[0];
    const float* rotation = (const float*)d_in[1];
    const float* points   = (const float*)d_in[2];
    float* out = (float*)d_out;
    (void)in_sizes; (void)n_in; (void)out_size; (void)d_ws; (void)ws_size;

    dim3 grid(NBATCH * (HWC / 256));  // 512 blocks
    dim3 block(256);
    post_prob_kernel<<<grid, block, 0, stream>>>(scale, rotation, points, out);
}